// Round 1
// baseline (535.977 us; speedup 1.0000x reference)
//
#include <hip/hip_runtime.h>

#define B_ 2
#define L_ 2048
#define D_ 512
#define H_ 8
#define DK 64
#define S_ 10240
#define SCALE 0.125f

#define QSZ (4096 * 512)  // B_*L_*D_

// ---------------------------------------------------------------------------
// Projections: y[n,e] = sum_d x[n,d]*W[e,d] + b[e], n = b*L + l, e = h*64+d'
// Output layout: row-major [B*L][512] (natural), z selects q/k/v.
// ---------------------------------------------------------------------------
__global__ __launch_bounds__(256) void proj_kernel(
    const float* __restrict__ x,
    const float* __restrict__ Wq, const float* __restrict__ bq,
    const float* __restrict__ Wk, const float* __restrict__ bk,
    const float* __restrict__ Wv, const float* __restrict__ bv,
    float* __restrict__ q, float* __restrict__ k, float* __restrict__ v)
{
    const int z = blockIdx.z;
    const float* W    = (z == 0) ? Wq : (z == 1) ? Wk : Wv;
    const float* bias = (z == 0) ? bq : (z == 1) ? bk : bv;
    float* outp       = (z == 0) ? q  : (z == 1) ? k  : v;

    const int n0 = blockIdx.x * 64;
    const int e0 = blockIdx.y * 64;
    const int t  = threadIdx.x;

    __shared__ float xs[32][64];
    __shared__ float sW[32][64];

    float acc[4][4];
#pragma unroll
    for (int i = 0; i < 4; i++)
#pragma unroll
        for (int j = 0; j < 4; j++) acc[i][j] = 0.f;

    const int tn = t & 15, te = t >> 4;   // compute mapping: 16x16 threads, 4x4 each
    const int ln = t >> 2, dc = (t & 3) * 8;  // staging mapping

    for (int d0 = 0; d0 < D_; d0 += 32) {
        __syncthreads();
        {
            const float4* xg = (const float4*)(x + (size_t)(n0 + ln) * D_ + d0 + dc);
            float4 a0 = xg[0], a1 = xg[1];
            const float4* wg = (const float4*)(W + (size_t)(e0 + ln) * D_ + d0 + dc);
            float4 b0 = wg[0], b1 = wg[1];
            xs[dc + 0][ln] = a0.x; xs[dc + 1][ln] = a0.y;
            xs[dc + 2][ln] = a0.z; xs[dc + 3][ln] = a0.w;
            xs[dc + 4][ln] = a1.x; xs[dc + 5][ln] = a1.y;
            xs[dc + 6][ln] = a1.z; xs[dc + 7][ln] = a1.w;
            sW[dc + 0][ln] = b0.x; sW[dc + 1][ln] = b0.y;
            sW[dc + 2][ln] = b0.z; sW[dc + 3][ln] = b0.w;
            sW[dc + 4][ln] = b1.x; sW[dc + 5][ln] = b1.y;
            sW[dc + 6][ln] = b1.z; sW[dc + 7][ln] = b1.w;
        }
        __syncthreads();
#pragma unroll 8
        for (int d = 0; d < 32; d++) {
            const float4 av = *(const float4*)&xs[d][tn * 4];
            const float4 bv4 = *(const float4*)&sW[d][te * 4];
            const float qa[4] = {av.x, av.y, av.z, av.w};
            const float ba[4] = {bv4.x, bv4.y, bv4.z, bv4.w};
#pragma unroll
            for (int i = 0; i < 4; i++)
#pragma unroll
                for (int j = 0; j < 4; j++)
                    acc[i][j] = fmaf(qa[i], ba[j], acc[i][j]);
        }
    }

    const float4 bb = *(const float4*)&bias[e0 + te * 4];
    const float badd[4] = {bb.x, bb.y, bb.z, bb.w};
#pragma unroll
    for (int i = 0; i < 4; i++) {
        const int n = n0 + tn * 4 + i;
        float4 r;
        r.x = acc[i][0] + badd[0];
        r.y = acc[i][1] + badd[1];
        r.z = acc[i][2] + badd[2];
        r.w = acc[i][3] + badd[3];
        *(float4*)&outp[(size_t)n * D_ + e0 + te * 4] = r;
    }
}

// ---------------------------------------------------------------------------
// Histogram of sampled indices
// ---------------------------------------------------------------------------
__global__ void hist_kernel(const int* __restrict__ samp, int* __restrict__ counts)
{
    const int i = blockIdx.x * 256 + threadIdx.x;
    if (i < S_) atomicAdd(&counts[samp[i]], 1);
}

// ---------------------------------------------------------------------------
// kbar[bh][e] = (1/S) * sum_j counts[j] * k[b, j, h*64+e]
// ---------------------------------------------------------------------------
__global__ __launch_bounds__(256) void kbar_kernel(
    const float* __restrict__ k, const int* __restrict__ counts,
    float* __restrict__ kbar)
{
    const int bh = blockIdx.x;
    const int b = bh >> 3, h = bh & 7;
    const int t = threadIdx.x;
    const int e = t & 63, jg = t >> 6;
    const float* kb = k + (size_t)b * L_ * D_ + h * DK;
    float s = 0.f;
    for (int j = jg; j < L_; j += 4) {
        const float c = (float)counts[j];
        s += c * kb[(size_t)j * D_ + e];
    }
    __shared__ float red[4][64];
    red[jg][e] = s;
    __syncthreads();
    if (t < 64) {
        const float tot = red[0][t] + red[1][t] + red[2][t] + red[3][t];
        kbar[bh * DK + t] = tot / (float)S_;
    }
}

// ---------------------------------------------------------------------------
// Masked max over sampled keys: Mpart[js][bh][l] = max_{j in js-range, count>0} q_l . k_j
// (unscaled dot; scale is a common positive factor, argmax-invariant)
// ---------------------------------------------------------------------------
__global__ __launch_bounds__(256) void mstat_kernel(
    const float* __restrict__ q, const float* __restrict__ k,
    const int* __restrict__ counts, float* __restrict__ Mpart)
{
    const int lt = blockIdx.x;   // 0..15 (l-tile of 128)
    const int bh = blockIdx.y;   // 0..15
    const int js = blockIdx.z;   // 0..3  (j-range of 512)
    const int b = bh >> 3, h = bh & 7;
    const int l0 = lt * 128;
    const int j0 = js * 512;
    const int t = threadIdx.x;

    __shared__ float qs[64][128];
    __shared__ float ks[64][64];
    __shared__ float cms[64];
    __shared__ float red[8][128];

    // stage q tile (128 rows x 64 d), transposed into qs[d][l]
    {
        const int l = t >> 1, dcq = (t & 1) * 32;
        const float* src = q + (size_t)(b * L_ + l0 + l) * D_ + h * DK + dcq;
#pragma unroll
        for (int c = 0; c < 8; c++) {
            const float4 r = *(const float4*)(src + c * 4);
            qs[dcq + c * 4 + 0][l] = r.x;
            qs[dcq + c * 4 + 1][l] = r.y;
            qs[dcq + c * 4 + 2][l] = r.z;
            qs[dcq + c * 4 + 3][l] = r.w;
        }
    }

    const int tl = t & 31, tj = t >> 5;   // thread owns l = tl*4..+3, j = tj*8..+7
    float m0[4] = {-3.9e38f, -3.9e38f, -3.9e38f, -3.9e38f};
    const float* kbase = k + (size_t)b * L_ * D_ + h * DK;

#pragma unroll 1
    for (int jt = 0; jt < 8; jt++) {
        const int jb = j0 + jt * 64;
        __syncthreads();
        {
            const int jj = t >> 2, dck = (t & 3) * 16;
            const float* src = kbase + (size_t)(jb + jj) * D_ + dck;
#pragma unroll
            for (int c = 0; c < 4; c++) {
                const float4 r = *(const float4*)(src + c * 4);
                ks[dck + c * 4 + 0][jj] = r.x;
                ks[dck + c * 4 + 1][jj] = r.y;
                ks[dck + c * 4 + 2][jj] = r.z;
                ks[dck + c * 4 + 3][jj] = r.w;
            }
            if (t < 64) cms[t] = (counts[jb + t] > 0) ? 0.f : -3.0e38f;
        }
        __syncthreads();

        float acc[4][8];
#pragma unroll
        for (int i = 0; i < 4; i++)
#pragma unroll
            for (int j = 0; j < 8; j++) acc[i][j] = 0.f;

#pragma unroll 8
        for (int d = 0; d < 64; d++) {
            const float4 qv = *(const float4*)&qs[d][tl * 4];
            const float4 k0v = *(const float4*)&ks[d][tj * 8];
            const float4 k1v = *(const float4*)&ks[d][tj * 8 + 4];
            const float qa[4] = {qv.x, qv.y, qv.z, qv.w};
            const float ka[8] = {k0v.x, k0v.y, k0v.z, k0v.w,
                                 k1v.x, k1v.y, k1v.z, k1v.w};
#pragma unroll
            for (int i = 0; i < 4; i++)
#pragma unroll
                for (int j = 0; j < 8; j++)
                    acc[i][j] = fmaf(qa[i], ka[j], acc[i][j]);
        }

#pragma unroll
        for (int i = 0; i < 4; i++)
#pragma unroll
            for (int j = 0; j < 8; j++)
                m0[i] = fmaxf(m0[i], acc[i][j] + cms[tj * 8 + j]);
    }

    __syncthreads();
#pragma unroll
    for (int i = 0; i < 4; i++) red[tj][tl * 4 + i] = m0[i];
    __syncthreads();
    if (t < 128) {
        float mm = red[0][t];
#pragma unroll
        for (int g = 1; g < 8; g++) mm = fmaxf(mm, red[g][t]);
        Mpart[(size_t)(js * 16 + bh) * L_ + l0 + t] = mm;
    }
}

// ---------------------------------------------------------------------------
// Argmax over l of (max_dot - q.kbar)  (scale factored out, positive)
// ---------------------------------------------------------------------------
__global__ __launch_bounds__(256) void argmax_kernel(
    const float* __restrict__ q, const float* __restrict__ kbar,
    const float* __restrict__ Mpart, int* __restrict__ U)
{
    const int bh = blockIdx.x;
    const int b = bh >> 3, h = bh & 7;
    const int t = threadIdx.x;
    __shared__ float kb[64];
    if (t < 64) kb[t] = kbar[bh * 64 + t];
    __syncthreads();

    float best = -3.9e38f;
    int besti = 0;
    for (int l = t; l < L_; l += 256) {
        const float* qr = q + (size_t)(b * L_ + l) * D_ + h * DK;
        float dot = 0.f;
#pragma unroll
        for (int c = 0; c < 16; c++) {
            const float4 qv = *(const float4*)(qr + c * 4);
            dot += qv.x * kb[c * 4] + qv.y * kb[c * 4 + 1] +
                   qv.z * kb[c * 4 + 2] + qv.w * kb[c * 4 + 3];
        }
        float mx = Mpart[(size_t)(0 * 16 + bh) * L_ + l];
        mx = fmaxf(mx, Mpart[(size_t)(1 * 16 + bh) * L_ + l]);
        mx = fmaxf(mx, Mpart[(size_t)(2 * 16 + bh) * L_ + l]);
        mx = fmaxf(mx, Mpart[(size_t)(3 * 16 + bh) * L_ + l]);
        const float val = mx - dot;
        if (val > best || (val == best && l < besti)) { best = val; besti = l; }
    }

    __shared__ float bv[256];
    __shared__ int bi[256];
    bv[t] = best; bi[t] = besti;
    __syncthreads();
    for (int s = 128; s > 0; s >>= 1) {
        if (t < s) {
            const float ov = bv[t + s]; const int oi = bi[t + s];
            if (ov > bv[t] || (ov == bv[t] && oi < bi[t])) { bv[t] = ov; bi[t] = oi; }
        }
        __syncthreads();
    }
    if (t == 0) U[bh] = bi[0];
}

// ---------------------------------------------------------------------------
// scores = scale * q_red . k_l  -> softmax -> ctx[bh][e] = sum_l attn_l v[l][e]
// ---------------------------------------------------------------------------
__global__ __launch_bounds__(256) void ctx_kernel(
    const float* __restrict__ q, const float* __restrict__ k,
    const float* __restrict__ v, const int* __restrict__ U,
    float* __restrict__ ctx)
{
    const int bh = blockIdx.x;
    const int b = bh >> 3, h = bh & 7;
    const int t = threadIdx.x;
    __shared__ float qr[64];
    __shared__ float sc[2048];
    __shared__ float redm[256];

    const int u = U[bh];
    if (t < 64) qr[t] = q[(size_t)(b * L_ + u) * D_ + h * DK + t];
    __syncthreads();

    float pmax = -3.9e38f;
    for (int l = t; l < L_; l += 256) {
        const float* kr = k + (size_t)(b * L_ + l) * D_ + h * DK;
        float dot = 0.f;
#pragma unroll
        for (int c = 0; c < 16; c++) {
            const float4 kv = *(const float4*)(kr + c * 4);
            dot += kv.x * qr[c * 4] + kv.y * qr[c * 4 + 1] +
                   kv.z * qr[c * 4 + 2] + kv.w * qr[c * 4 + 3];
        }
        dot *= SCALE;
        sc[l] = dot;
        pmax = fmaxf(pmax, dot);
    }
    redm[t] = pmax;
    __syncthreads();
    for (int s = 128; s > 0; s >>= 1) {
        if (t < s) redm[t] = fmaxf(redm[t], redm[t + s]);
        __syncthreads();
    }
    const float smax = redm[0];
    __syncthreads();

    float psum = 0.f;
    for (int l = t; l < L_; l += 256) {
        const float w = expf(sc[l] - smax);
        sc[l] = w;
        psum += w;
    }
    redm[t] = psum;
    __syncthreads();
    for (int s = 128; s > 0; s >>= 1) {
        if (t < s) redm[t] += redm[t + s];
        __syncthreads();
    }
    const float denom = redm[0];

    const int e = t & 63, lg = t >> 6;
    const float* vb = v + (size_t)b * L_ * D_ + h * DK + e;
    float cacc = 0.f;
    for (int l = lg; l < L_; l += 4) cacc += sc[l] * vb[(size_t)l * D_];

    __shared__ float redc[4][64];
    redc[lg][e] = cacc;
    __syncthreads();
    if (t < 64)
        ctx[bh * 64 + t] = (redc[0][t] + redc[1][t] + redc[2][t] + redc[3][t]) / denom;
}

// ---------------------------------------------------------------------------
// out[b,l,e] = sum_d ctx[b][d] * Wo[e,d] + bo[e]   (same row for every l)
// Each block recomputes the 512-row (cheap) and writes a 64-row slice.
// ---------------------------------------------------------------------------
__global__ __launch_bounds__(256) void out_kernel(
    const float* __restrict__ ctx, const float* __restrict__ Wo,
    const float* __restrict__ bo, float* __restrict__ out)
{
    const int b = blockIdx.x;    // 0..1
    const int sl = blockIdx.y;   // 0..31
    const int t = threadIdx.x;
    __shared__ float cb[512];
    __shared__ float row[512];

    cb[t] = ctx[b * 512 + t];
    cb[t + 256] = ctx[b * 512 + 256 + t];
    __syncthreads();

#pragma unroll
    for (int r = 0; r < 2; r++) {
        const int e = t + r * 256;
        const float* wr = Wo + (size_t)e * D_;
        float acc = 0.f;
#pragma unroll 8
        for (int c = 0; c < 128; c++) {
            const float4 wv = *(const float4*)(wr + c * 4);
            acc += wv.x * cb[c * 4] + wv.y * cb[c * 4 + 1] +
                   wv.z * cb[c * 4 + 2] + wv.w * cb[c * 4 + 3];
        }
        row[e] = acc + bo[e];
    }
    __syncthreads();

    const float4* r4 = (const float4*)row;
    float4* o4 = (float4*)(out + ((size_t)b * L_ + sl * 64) * D_);
    for (int i = t; i < 64 * 128; i += 256) {
        const int l = i >> 7, c = i & 127;
        o4[l * 128 + c] = r4[c];
    }
}

// ---------------------------------------------------------------------------
extern "C" void kernel_launch(void* const* d_in, const int* in_sizes, int n_in,
                              void* d_out, int out_size, void* d_ws, size_t ws_size,
                              hipStream_t stream)
{
    const float* x   = (const float*)d_in[0];
    const int* samp  = (const int*)d_in[1];
    const float* Wq  = (const float*)d_in[2];
    const float* bq  = (const float*)d_in[3];
    const float* Wk  = (const float*)d_in[4];
    const float* bk  = (const float*)d_in[5];
    const float* Wv  = (const float*)d_in[6];
    const float* bv  = (const float*)d_in[7];
    const float* Wo  = (const float*)d_in[8];
    const float* bo  = (const float*)d_in[9];
    float* out = (float*)d_out;

    float* ws = (float*)d_ws;
    float* q    = ws;                 // 2,097,152 floats
    float* k    = q + QSZ;
    float* v    = k + QSZ;
    float* kbar = v + QSZ;            // 16*64
    float* Mpart = kbar + 1024;       // 4*16*2048
    float* ctx  = Mpart + 131072;     // 16*64
    int* counts = (int*)(ctx + 1024); // 2048 ints
    int* U      = counts + 2048;      // 16 ints

    hipMemsetAsync(counts, 0, 2048 * sizeof(int), stream);
    proj_kernel<<<dim3(64, 8, 3), 256, 0, stream>>>(x, Wq, bq, Wk, bk, Wv, bv, q, k, v);
    hist_kernel<<<40, 256, 0, stream>>>(samp, counts);
    kbar_kernel<<<16, 256, 0, stream>>>(k, counts, kbar);
    mstat_kernel<<<dim3(16, 16, 4), 256, 0, stream>>>(q, k, counts, Mpart);
    argmax_kernel<<<16, 256, 0, stream>>>(q, kbar, Mpart, U);
    ctx_kernel<<<16, 256, 0, stream>>>(q, k, v, U, ctx);
    out_kernel<<<dim3(2, 32), 256, 0, stream>>>(ctx, Wo, bo, out);
}

// Round 2
// 278.424 us; speedup vs baseline: 1.9250x; 1.9250x over previous
//
#include <hip/hip_runtime.h>

#define B_ 2
#define L_ 2048
#define D_ 512
#define H_ 8
#define DK 64
#define S_ 10240
#define SCALE 0.125f

#define QSZ (4096 * 512)  // B_*L_*D_

// ---------------------------------------------------------------------------
// Projections: y[n,e] = sum_d x[n,d]*W[e,d] + b[e], n = b*L + l, e = h*64+d'
// ---------------------------------------------------------------------------
__global__ __launch_bounds__(256) void proj_kernel(
    const float* __restrict__ x,
    const float* __restrict__ Wq, const float* __restrict__ bq,
    const float* __restrict__ Wk, const float* __restrict__ bk,
    const float* __restrict__ Wv, const float* __restrict__ bv,
    float* __restrict__ q, float* __restrict__ k, float* __restrict__ v)
{
    const int z = blockIdx.z;
    const float* W    = (z == 0) ? Wq : (z == 1) ? Wk : Wv;
    const float* bias = (z == 0) ? bq : (z == 1) ? bk : bv;
    float* outp       = (z == 0) ? q  : (z == 1) ? k  : v;

    const int n0 = blockIdx.x * 64;
    const int e0 = blockIdx.y * 64;
    const int t  = threadIdx.x;

    __shared__ float xs[32][64];
    __shared__ float sW[32][64];

    float acc[4][4];
#pragma unroll
    for (int i = 0; i < 4; i++)
#pragma unroll
        for (int j = 0; j < 4; j++) acc[i][j] = 0.f;

    const int tn = t & 15, te = t >> 4;
    const int ln = t >> 2, dc = (t & 3) * 8;

    for (int d0 = 0; d0 < D_; d0 += 32) {
        __syncthreads();
        {
            const float4* xg = (const float4*)(x + (size_t)(n0 + ln) * D_ + d0 + dc);
            float4 a0 = xg[0], a1 = xg[1];
            const float4* wg = (const float4*)(W + (size_t)(e0 + ln) * D_ + d0 + dc);
            float4 b0 = wg[0], b1 = wg[1];
            xs[dc + 0][ln] = a0.x; xs[dc + 1][ln] = a0.y;
            xs[dc + 2][ln] = a0.z; xs[dc + 3][ln] = a0.w;
            xs[dc + 4][ln] = a1.x; xs[dc + 5][ln] = a1.y;
            xs[dc + 6][ln] = a1.z; xs[dc + 7][ln] = a1.w;
            sW[dc + 0][ln] = b0.x; sW[dc + 1][ln] = b0.y;
            sW[dc + 2][ln] = b0.z; sW[dc + 3][ln] = b0.w;
            sW[dc + 4][ln] = b1.x; sW[dc + 5][ln] = b1.y;
            sW[dc + 6][ln] = b1.z; sW[dc + 7][ln] = b1.w;
        }
        __syncthreads();
#pragma unroll 8
        for (int d = 0; d < 32; d++) {
            const float4 av = *(const float4*)&xs[d][tn * 4];
            const float4 bv4 = *(const float4*)&sW[d][te * 4];
            const float qa[4] = {av.x, av.y, av.z, av.w};
            const float ba[4] = {bv4.x, bv4.y, bv4.z, bv4.w};
#pragma unroll
            for (int i = 0; i < 4; i++)
#pragma unroll
                for (int j = 0; j < 4; j++)
                    acc[i][j] = fmaf(qa[i], ba[j], acc[i][j]);
        }
    }

    const float4 bb = *(const float4*)&bias[e0 + te * 4];
    const float badd[4] = {bb.x, bb.y, bb.z, bb.w};
#pragma unroll
    for (int i = 0; i < 4; i++) {
        const int n = n0 + tn * 4 + i;
        float4 r;
        r.x = acc[i][0] + badd[0];
        r.y = acc[i][1] + badd[1];
        r.z = acc[i][2] + badd[2];
        r.w = acc[i][3] + badd[3];
        *(float4*)&outp[(size_t)n * D_ + e0 + te * 4] = r;
    }
}

// ---------------------------------------------------------------------------
__global__ void hist_kernel(const int* __restrict__ samp, int* __restrict__ counts)
{
    const int i = blockIdx.x * 256 + threadIdx.x;
    if (i < S_) atomicAdd(&counts[samp[i]], 1);
}

// ---------------------------------------------------------------------------
// kbar partials: kbar_part[(bh*8+c)*64+e] = sum_{j in chunk} counts[j]*k[b,j,h*64+e]
// ---------------------------------------------------------------------------
__global__ __launch_bounds__(256) void kbar_part_kernel(
    const float* __restrict__ k, const int* __restrict__ counts,
    float* __restrict__ kbar_part)
{
    const int bh = blockIdx.x, c = blockIdx.y;
    const int b = bh >> 3, h = bh & 7;
    const int j0 = c * 256;
    const int t = threadIdx.x;
    const int e = t & 63, jg = t >> 6;
    const float* kb = k + (size_t)b * L_ * D_ + h * DK + e;
    float s = 0.f;
    for (int j = j0 + jg; j < j0 + 256; j += 4)
        s += (float)counts[j] * kb[(size_t)j * D_];
    __shared__ float red[4][64];
    red[jg][e] = s;
    __syncthreads();
    if (t < 64)
        kbar_part[(size_t)(bh * 8 + c) * 64 + t] =
            red[0][t] + red[1][t] + red[2][t] + red[3][t];
}

// ---------------------------------------------------------------------------
// Masked max over sampled keys (unscaled; scale argmax-invariant)
// ---------------------------------------------------------------------------
__global__ __launch_bounds__(256) void mstat_kernel(
    const float* __restrict__ q, const float* __restrict__ k,
    const int* __restrict__ counts, float* __restrict__ Mpart)
{
    const int lt = blockIdx.x;   // l-tile of 128
    const int bh = blockIdx.y;
    const int js = blockIdx.z;   // j-range of 512
    const int b = bh >> 3, h = bh & 7;
    const int l0 = lt * 128;
    const int j0 = js * 512;
    const int t = threadIdx.x;

    __shared__ float qs[64][128];
    __shared__ float ks[64][64];
    __shared__ float cms[64];
    __shared__ float red[8][128];

    {
        const int l = t >> 1, dcq = (t & 1) * 32;
        const float* src = q + (size_t)(b * L_ + l0 + l) * D_ + h * DK + dcq;
#pragma unroll
        for (int c = 0; c < 8; c++) {
            const float4 r = *(const float4*)(src + c * 4);
            qs[dcq + c * 4 + 0][l] = r.x;
            qs[dcq + c * 4 + 1][l] = r.y;
            qs[dcq + c * 4 + 2][l] = r.z;
            qs[dcq + c * 4 + 3][l] = r.w;
        }
    }

    const int tl = t & 31, tj = t >> 5;
    float m0[4] = {-3.9e38f, -3.9e38f, -3.9e38f, -3.9e38f};
    const float* kbase = k + (size_t)b * L_ * D_ + h * DK;

#pragma unroll 1
    for (int jt = 0; jt < 8; jt++) {
        const int jb = j0 + jt * 64;
        __syncthreads();
        {
            const int jj = t >> 2, dck = (t & 3) * 16;
            const float* src = kbase + (size_t)(jb + jj) * D_ + dck;
#pragma unroll
            for (int c = 0; c < 4; c++) {
                const float4 r = *(const float4*)(src + c * 4);
                ks[dck + c * 4 + 0][jj] = r.x;
                ks[dck + c * 4 + 1][jj] = r.y;
                ks[dck + c * 4 + 2][jj] = r.z;
                ks[dck + c * 4 + 3][jj] = r.w;
            }
            if (t < 64) cms[t] = (counts[jb + t] > 0) ? 0.f : -3.0e38f;
        }
        __syncthreads();

        float acc[4][8];
#pragma unroll
        for (int i = 0; i < 4; i++)
#pragma unroll
            for (int j = 0; j < 8; j++) acc[i][j] = 0.f;

#pragma unroll 8
        for (int d = 0; d < 64; d++) {
            const float4 qv = *(const float4*)&qs[d][tl * 4];
            const float4 k0v = *(const float4*)&ks[d][tj * 8];
            const float4 k1v = *(const float4*)&ks[d][tj * 8 + 4];
            const float qa[4] = {qv.x, qv.y, qv.z, qv.w};
            const float ka[8] = {k0v.x, k0v.y, k0v.z, k0v.w,
                                 k1v.x, k1v.y, k1v.z, k1v.w};
#pragma unroll
            for (int i = 0; i < 4; i++)
#pragma unroll
                for (int j = 0; j < 8; j++)
                    acc[i][j] = fmaf(qa[i], ka[j], acc[i][j]);
        }

#pragma unroll
        for (int i = 0; i < 4; i++)
#pragma unroll
            for (int j = 0; j < 8; j++)
                m0[i] = fmaxf(m0[i], acc[i][j] + cms[tj * 8 + j]);
    }

    __syncthreads();
#pragma unroll
    for (int i = 0; i < 4; i++) red[tj][tl * 4 + i] = m0[i];
    __syncthreads();
    if (t < 128) {
        float mm = red[0][t];
#pragma unroll
        for (int g = 1; g < 8; g++) mm = fmaxf(mm, red[g][t]);
        Mpart[(size_t)(js * 16 + bh) * L_ + l0 + t] = mm;
    }
}

// ---------------------------------------------------------------------------
// Argmax stage 1: per (bh, chunk of 256 l) best (val=max_dot - q.kbar, idx)
// ---------------------------------------------------------------------------
__global__ __launch_bounds__(256) void argmax1_kernel(
    const float* __restrict__ q, const float* __restrict__ kbar_part,
    const float* __restrict__ Mpart, float* __restrict__ bestv,
    int* __restrict__ besti)
{
    const int bh = blockIdx.x, c = blockIdx.y;
    const int b = bh >> 3, h = bh & 7;
    const int l0 = c * 256;
    const int t = threadIdx.x;

    __shared__ float kb[64];
    if (t < 64) {
        float s = 0.f;
#pragma unroll
        for (int p = 0; p < 8; p++) s += kbar_part[(size_t)(bh * 8 + p) * 64 + t];
        kb[t] = s * (1.0f / (float)S_);
    }
    __syncthreads();

    const int l = l0 + t;
    const float* qr = q + (size_t)(b * L_ + l) * D_ + h * DK;
    float dot = 0.f;
#pragma unroll
    for (int cc = 0; cc < 16; cc++) {
        const float4 qv = *(const float4*)(qr + cc * 4);
        dot += qv.x * kb[cc * 4] + qv.y * kb[cc * 4 + 1] +
               qv.z * kb[cc * 4 + 2] + qv.w * kb[cc * 4 + 3];
    }
    float mx = Mpart[(size_t)(0 * 16 + bh) * L_ + l];
    mx = fmaxf(mx, Mpart[(size_t)(1 * 16 + bh) * L_ + l]);
    mx = fmaxf(mx, Mpart[(size_t)(2 * 16 + bh) * L_ + l]);
    mx = fmaxf(mx, Mpart[(size_t)(3 * 16 + bh) * L_ + l]);
    const float val = mx - dot;

    __shared__ float bvs[256];
    __shared__ int bis[256];
    bvs[t] = val; bis[t] = l;
    __syncthreads();
    for (int s = 128; s > 0; s >>= 1) {
        if (t < s) {
            const float ov = bvs[t + s]; const int oi = bis[t + s];
            if (ov > bvs[t] || (ov == bvs[t] && oi < bis[t])) { bvs[t] = ov; bis[t] = oi; }
        }
        __syncthreads();
    }
    if (t == 0) { bestv[bh * 8 + c] = bvs[0]; besti[bh * 8 + c] = bis[0]; }
}

// ---------------------------------------------------------------------------
// Argmax stage 2: 1 block. Ascending chunks, strict > keeps first occurrence.
// ---------------------------------------------------------------------------
__global__ void argmax2_kernel(const float* __restrict__ bestv,
                               const int* __restrict__ besti, int* __restrict__ U)
{
    const int t = threadIdx.x;
    if (t < 16) {
        float best = -3.9e38f;
        int bi = 0;
#pragma unroll
        for (int c = 0; c < 8; c++) {
            const float v = bestv[t * 8 + c];
            if (v > best) { best = v; bi = besti[t * 8 + c]; }
        }
        U[t] = bi;
    }
}

// ---------------------------------------------------------------------------
// ctx stage 1: per (bh, chunk of 128 l): m, s, weighted-V partial
// ---------------------------------------------------------------------------
__global__ __launch_bounds__(256) void ctx_part_kernel(
    const float* __restrict__ q, const float* __restrict__ k,
    const float* __restrict__ v, const int* __restrict__ U,
    float* __restrict__ ctx_part, float* __restrict__ cm, float* __restrict__ cs)
{
    const int bh = blockIdx.x, c = blockIdx.y;   // 16 x 16
    const int b = bh >> 3, h = bh & 7;
    const int l0 = c * 128;
    const int t = threadIdx.x;

    __shared__ float qr[64];
    __shared__ float w[128];
    __shared__ float red[128];
    __shared__ float redc[4][64];

    const int u = U[bh];
    if (t < 64) qr[t] = q[(size_t)(b * L_ + u) * D_ + h * DK + t];
    __syncthreads();

    // dot: 2 threads per row, 32 d each
    {
        const int row = t >> 1, half = t & 1;
        const float* kr = k + (size_t)(b * L_ + l0 + row) * D_ + h * DK + half * 32;
        float dot = 0.f;
#pragma unroll
        for (int cc = 0; cc < 8; cc++) {
            const float4 kv = *(const float4*)(kr + cc * 4);
            dot += kv.x * qr[half * 32 + cc * 4] + kv.y * qr[half * 32 + cc * 4 + 1] +
                   kv.z * qr[half * 32 + cc * 4 + 2] + kv.w * qr[half * 32 + cc * 4 + 3];
        }
        dot += __shfl_xor(dot, 1);
        if (half == 0) w[row] = dot * SCALE;
    }
    __syncthreads();

    // max over 128
    if (t < 128) red[t] = w[t];
    __syncthreads();
    for (int s = 64; s > 0; s >>= 1) {
        if (t < s) red[t] = fmaxf(red[t], red[t + s]);
        __syncthreads();
    }
    const float m = red[0];
    __syncthreads();

    // exp + sum
    if (t < 128) { const float e = expf(w[t] - m); w[t] = e; red[t] = e; }
    __syncthreads();
    for (int s = 64; s > 0; s >>= 1) {
        if (t < s) red[t] += red[t + s];
        __syncthreads();
    }
    const float ssum = red[0];

    // weighted V partial
    const int e = t & 63, lg = t >> 6;
    const float* vb = v + (size_t)(b * L_ + l0) * D_ + h * DK + e;
    float cacc = 0.f;
#pragma unroll 4
    for (int l = lg; l < 128; l += 4) cacc += w[l] * vb[(size_t)l * D_];
    redc[lg][e] = cacc;
    __syncthreads();
    if (t < 64)
        ctx_part[(size_t)(bh * 16 + c) * 64 + t] =
            redc[0][t] + redc[1][t] + redc[2][t] + redc[3][t];
    if (t == 0) { cm[bh * 16 + c] = m; cs[bh * 16 + c] = ssum; }
}

// ---------------------------------------------------------------------------
// ctx combine: 16 blocks x 64 threads
// ---------------------------------------------------------------------------
__global__ void ctx_combine_kernel(const float* __restrict__ ctx_part,
                                   const float* __restrict__ cm,
                                   const float* __restrict__ cs,
                                   float* __restrict__ ctx)
{
    const int bh = blockIdx.x;
    const int e = threadIdx.x;   // 64 threads
    float M = -3.9e38f;
#pragma unroll
    for (int c = 0; c < 16; c++) M = fmaxf(M, cm[bh * 16 + c]);
    float denom = 0.f, acc = 0.f;
#pragma unroll
    for (int c = 0; c < 16; c++) {
        const float f = expf(cm[bh * 16 + c] - M);
        denom += f * cs[bh * 16 + c];
        acc   += f * ctx_part[(size_t)(bh * 16 + c) * 64 + e];
    }
    ctx[bh * 64 + e] = acc / denom;
}

// ---------------------------------------------------------------------------
// out[b,l,e] = ctx[b] . Wo[e,:] + bo[e], broadcast over l
// ---------------------------------------------------------------------------
__global__ __launch_bounds__(256) void out_kernel(
    const float* __restrict__ ctx, const float* __restrict__ Wo,
    const float* __restrict__ bo, float* __restrict__ out)
{
    const int b = blockIdx.x;    // 0..1
    const int sl = blockIdx.y;   // 0..63 (32-row slices)
    const int t = threadIdx.x;
    __shared__ float cb[512];
    __shared__ float row[512];

    cb[t] = ctx[b * 512 + t];
    cb[t + 256] = ctx[b * 512 + 256 + t];
    __syncthreads();

#pragma unroll
    for (int r = 0; r < 2; r++) {
        const int e = t + r * 256;
        const float* wr = Wo + (size_t)e * D_;
        float acc = 0.f;
#pragma unroll 8
        for (int c = 0; c < 128; c++) {
            const float4 wv = *(const float4*)(wr + c * 4);
            acc += wv.x * cb[c * 4] + wv.y * cb[c * 4 + 1] +
                   wv.z * cb[c * 4 + 2] + wv.w * cb[c * 4 + 3];
        }
        row[e] = acc + bo[e];
    }
    __syncthreads();

    const float4* r4 = (const float4*)row;
    float4* o4 = (float4*)(out + ((size_t)b * L_ + sl * 32) * D_);
    for (int i = t; i < 32 * 128; i += 256) {
        const int l = i >> 7, c = i & 127;
        o4[l * 128 + c] = r4[c];
    }
}

// ---------------------------------------------------------------------------
extern "C" void kernel_launch(void* const* d_in, const int* in_sizes, int n_in,
                              void* d_out, int out_size, void* d_ws, size_t ws_size,
                              hipStream_t stream)
{
    const float* x   = (const float*)d_in[0];
    const int* samp  = (const int*)d_in[1];
    const float* Wq  = (const float*)d_in[2];
    const float* bq  = (const float*)d_in[3];
    const float* Wk  = (const float*)d_in[4];
    const float* bk  = (const float*)d_in[5];
    const float* Wv  = (const float*)d_in[6];
    const float* bv  = (const float*)d_in[7];
    const float* Wo  = (const float*)d_in[8];
    const float* bo  = (const float*)d_in[9];
    float* out = (float*)d_out;

    float* ws = (float*)d_ws;
    float* q         = ws;                    // 2,097,152
    float* k         = q + QSZ;
    float* v         = k + QSZ;
    float* Mpart     = v + QSZ;               // 131072
    float* kbar_part = Mpart + 131072;        // 8192
    float* ctx_part  = kbar_part + 8192;      // 16384
    float* cm        = ctx_part + 16384;      // 256
    float* cs        = cm + 256;              // 256
    float* bestv     = cs + 256;              // 128
    float* ctx       = bestv + 128;           // 1024
    int* counts      = (int*)(ctx + 1024);    // 2048
    int* besti       = counts + 2048;         // 128
    int* U           = besti + 128;           // 16

    hipMemsetAsync(counts, 0, 2048 * sizeof(int), stream);
    proj_kernel<<<dim3(64, 8, 3), 256, 0, stream>>>(x, Wq, bq, Wk, bk, Wv, bv, q, k, v);
    hist_kernel<<<40, 256, 0, stream>>>(samp, counts);
    kbar_part_kernel<<<dim3(16, 8), 256, 0, stream>>>(k, counts, kbar_part);
    mstat_kernel<<<dim3(16, 16, 4), 256, 0, stream>>>(q, k, counts, Mpart);
    argmax1_kernel<<<dim3(16, 8), 256, 0, stream>>>(q, kbar_part, Mpart, bestv, besti);
    argmax2_kernel<<<1, 64, 0, stream>>>(bestv, besti, U);
    ctx_part_kernel<<<dim3(16, 16), 256, 0, stream>>>(q, k, v, U, ctx_part, cm, cs);
    ctx_combine_kernel<<<16, 64, 0, stream>>>(ctx_part, cm, cs, ctx);
    out_kernel<<<dim3(2, 64), 256, 0, stream>>>(ctx, Wo, bo, out);
}

// Round 3
// 210.136 us; speedup vs baseline: 2.5506x; 1.3250x over previous
//
#include <hip/hip_runtime.h>

#define B_ 2
#define L_ 2048
#define D_ 512
#define H_ 8
#define DK 64
#define S_ 10240
#define SCALE 0.125f
#define MP_SLICES 16

#define QSZ (4096 * 512)  // B_*L_*D_ elements

typedef _Float16 f16;
typedef __attribute__((ext_vector_type(8))) _Float16 f16x8;
typedef __attribute__((ext_vector_type(4))) float f32x4;

// ---------------------------------------------------------------------------
// Projections: y[n,e] = sum_d x[n,d]*W[e,d] + b[e]
// z=0 -> qh/ql (f16 split), z=1 -> kh/kl, z=2 -> v (fp32)
// ---------------------------------------------------------------------------
__global__ __launch_bounds__(256) void proj_kernel(
    const float* __restrict__ x,
    const float* __restrict__ Wq, const float* __restrict__ bq,
    const float* __restrict__ Wk, const float* __restrict__ bk,
    const float* __restrict__ Wv, const float* __restrict__ bv,
    f16* __restrict__ qh, f16* __restrict__ ql,
    f16* __restrict__ kh, f16* __restrict__ kl,
    float* __restrict__ v)
{
    const int z = blockIdx.z;
    const float* W    = (z == 0) ? Wq : (z == 1) ? Wk : Wv;
    const float* bias = (z == 0) ? bq : (z == 1) ? bk : bv;

    const int n0 = blockIdx.x * 64;
    const int e0 = blockIdx.y * 64;
    const int t  = threadIdx.x;

    __shared__ float xs[32][64];
    __shared__ float sW[32][64];

    float acc[4][4];
#pragma unroll
    for (int i = 0; i < 4; i++)
#pragma unroll
        for (int j = 0; j < 4; j++) acc[i][j] = 0.f;

    const int tn = t & 15, te = t >> 4;
    const int ln = t >> 2, dc = (t & 3) * 8;

    for (int d0 = 0; d0 < D_; d0 += 32) {
        __syncthreads();
        {
            const float4* xg = (const float4*)(x + (size_t)(n0 + ln) * D_ + d0 + dc);
            float4 a0 = xg[0], a1 = xg[1];
            const float4* wg = (const float4*)(W + (size_t)(e0 + ln) * D_ + d0 + dc);
            float4 b0 = wg[0], b1 = wg[1];
            xs[dc + 0][ln] = a0.x; xs[dc + 1][ln] = a0.y;
            xs[dc + 2][ln] = a0.z; xs[dc + 3][ln] = a0.w;
            xs[dc + 4][ln] = a1.x; xs[dc + 5][ln] = a1.y;
            xs[dc + 6][ln] = a1.z; xs[dc + 7][ln] = a1.w;
            sW[dc + 0][ln] = b0.x; sW[dc + 1][ln] = b0.y;
            sW[dc + 2][ln] = b0.z; sW[dc + 3][ln] = b0.w;
            sW[dc + 4][ln] = b1.x; sW[dc + 5][ln] = b1.y;
            sW[dc + 6][ln] = b1.z; sW[dc + 7][ln] = b1.w;
        }
        __syncthreads();
#pragma unroll 8
        for (int d = 0; d < 32; d++) {
            const float4 av = *(const float4*)&xs[d][tn * 4];
            const float4 bv4 = *(const float4*)&sW[d][te * 4];
            const float qa[4] = {av.x, av.y, av.z, av.w};
            const float ba[4] = {bv4.x, bv4.y, bv4.z, bv4.w};
#pragma unroll
            for (int i = 0; i < 4; i++)
#pragma unroll
                for (int j = 0; j < 4; j++)
                    acc[i][j] = fmaf(qa[i], ba[j], acc[i][j]);
        }
    }

    const float4 bb = *(const float4*)&bias[e0 + te * 4];
    const float badd[4] = {bb.x, bb.y, bb.z, bb.w};

    if (z == 2) {
#pragma unroll
        for (int i = 0; i < 4; i++) {
            const int n = n0 + tn * 4 + i;
            float4 r;
            r.x = acc[i][0] + badd[0];
            r.y = acc[i][1] + badd[1];
            r.z = acc[i][2] + badd[2];
            r.w = acc[i][3] + badd[3];
            *(float4*)&v[(size_t)n * D_ + e0 + te * 4] = r;
        }
    } else {
        f16* oh = (z == 0) ? qh : kh;
        f16* ol = (z == 0) ? ql : kl;
        union H4 { f16 h[4]; uint2 u; };
#pragma unroll
        for (int i = 0; i < 4; i++) {
            const int n = n0 + tn * 4 + i;
            H4 hh, llv;
#pragma unroll
            for (int j = 0; j < 4; j++) {
                const float y = acc[i][j] + badd[j];
                hh.h[j] = (f16)y;
                llv.h[j] = (f16)(y - (float)hh.h[j]);
            }
            *(uint2*)&oh[(size_t)n * D_ + e0 + te * 4] = hh.u;
            *(uint2*)&ol[(size_t)n * D_ + e0 + te * 4] = llv.u;
        }
    }
}

// ---------------------------------------------------------------------------
__global__ void hist_kernel(const int* __restrict__ samp, int* __restrict__ counts)
{
    const int i = blockIdx.x * 256 + threadIdx.x;
    if (i < S_) atomicAdd(&counts[samp[i]], 1);
}

// ---------------------------------------------------------------------------
// kbar partials (k reconstructed from f16 hi+lo)
// ---------------------------------------------------------------------------
__global__ __launch_bounds__(256) void kbar_part_kernel(
    const f16* __restrict__ kh, const f16* __restrict__ kl,
    const int* __restrict__ counts, float* __restrict__ kbar_part)
{
    const int bh = blockIdx.x, c = blockIdx.y;
    const int b = bh >> 3, h = bh & 7;
    const int j0 = c * 256;
    const int t = threadIdx.x;
    const int e = t & 63, jg = t >> 6;
    const f16* kbh = kh + (size_t)b * L_ * D_ + h * DK + e;
    const f16* kbl = kl + (size_t)b * L_ * D_ + h * DK + e;
    float s = 0.f;
    for (int j = j0 + jg; j < j0 + 256; j += 4) {
        const float kv = (float)kbh[(size_t)j * D_] + (float)kbl[(size_t)j * D_];
        s += (float)counts[j] * kv;
    }
    __shared__ float red[4][64];
    red[jg][e] = s;
    __syncthreads();
    if (t < 64)
        kbar_part[(size_t)(bh * 8 + c) * 64 + t] =
            red[0][t] + red[1][t] + red[2][t] + red[3][t];
}

// ---------------------------------------------------------------------------
// mstat via split-f16 MFMA: per (ltile128, bh, jtile128) block, masked row-max
// of Q.K^T (unscaled).  3-product split: hh + hl + lh, fp32 accumulate.
// ---------------------------------------------------------------------------
__global__ __launch_bounds__(256) void mstat_kernel(
    const f16* __restrict__ qh, const f16* __restrict__ ql,
    const f16* __restrict__ kh, const f16* __restrict__ kl,
    const int* __restrict__ counts, float* __restrict__ Mpart)
{
    const int lt16 = blockIdx.x;  // l-tile of 128
    const int bh   = blockIdx.y;
    const int jt16 = blockIdx.z;  // j-tile of 128
    const int b = bh >> 3, h = bh & 7;
    const int l0 = lt16 * 128, j0 = jt16 * 128;
    const int t = threadIdx.x;

    // 4 x 16 KB = 64 KB exactly (2 blocks/CU)
    __shared__ __align__(16) f16 qsh[128 * 64];
    __shared__ __align__(16) f16 qsl[128 * 64];
    __shared__ __align__(16) f16 ksh[128 * 64];
    __shared__ __align__(16) f16 ksl[128 * 64];

    // stage: 128 rows x 64 halves per array, 16B chunks, XOR-swizzled (c ^ row&7)
    {
        const size_t qbase = (size_t)(b * L_ + l0) * D_ + h * DK;
        const size_t kbase = (size_t)(b * L_ + j0) * D_ + h * DK;
#pragma unroll
        for (int i = 0; i < 4; i++) {
            const int g = i * 256 + t;
            const int row = g >> 3, c = g & 7;
            const int cs = c ^ (row & 7);
            const size_t go = (size_t)row * D_ + c * 8;
            const int lo = row * 64 + cs * 8;
            *(uint4*)&qsh[lo] = *(const uint4*)&qh[qbase + go];
            *(uint4*)&qsl[lo] = *(const uint4*)&ql[qbase + go];
            *(uint4*)&ksh[lo] = *(const uint4*)&kh[kbase + go];
            *(uint4*)&ksl[lo] = *(const uint4*)&kl[kbase + go];
        }
    }
    __syncthreads();

    const int lane = t & 63, wid = t >> 6;
    const int wr = wid >> 1, wc = wid & 1;   // wave tile: rows wr*64, cols wc*64
    const int lrow = lane & 15, lk = lane >> 4;

    f32x4 acc[4][4];
#pragma unroll
    for (int i = 0; i < 4; i++)
#pragma unroll
        for (int j = 0; j < 4; j++)
#pragma unroll
            for (int r = 0; r < 4; r++) acc[i][j][r] = 0.f;

#pragma unroll
    for (int kk = 0; kk < 2; kk++) {
        f16x8 ah[4], al[4], bh_[4], bl_[4];
#pragma unroll
        for (int lt = 0; lt < 4; lt++) {
            const int row = wr * 64 + lt * 16 + lrow;
            const int cs = (kk * 4 + lk) ^ (row & 7);
            const int o = row * 64 + cs * 8;
            ah[lt] = *(const f16x8*)&qsh[o];
            al[lt] = *(const f16x8*)&qsl[o];
        }
#pragma unroll
        for (int jt = 0; jt < 4; jt++) {
            const int row = wc * 64 + jt * 16 + lrow;
            const int cs = (kk * 4 + lk) ^ (row & 7);
            const int o = row * 64 + cs * 8;
            bh_[jt] = *(const f16x8*)&ksh[o];
            bl_[jt] = *(const f16x8*)&ksl[o];
        }
#pragma unroll
        for (int lt = 0; lt < 4; lt++)
#pragma unroll
            for (int jt = 0; jt < 4; jt++) {
                acc[lt][jt] = __builtin_amdgcn_mfma_f32_16x16x32_f16(
                    ah[lt], bh_[jt], acc[lt][jt], 0, 0, 0);
                acc[lt][jt] = __builtin_amdgcn_mfma_f32_16x16x32_f16(
                    ah[lt], bl_[jt], acc[lt][jt], 0, 0, 0);
                acc[lt][jt] = __builtin_amdgcn_mfma_f32_16x16x32_f16(
                    al[lt], bh_[jt], acc[lt][jt], 0, 0, 0);
            }
    }

    // masked row-max.  col of lane (per jt) = j0 + wc*64 + jt*16 + lrow
    float rmax[4][4];
#pragma unroll
    for (int lt = 0; lt < 4; lt++)
#pragma unroll
        for (int r = 0; r < 4; r++) rmax[lt][r] = -3.9e38f;

#pragma unroll
    for (int jt = 0; jt < 4; jt++) {
        const int cj = j0 + wc * 64 + jt * 16 + lrow;
        const float addend = (counts[cj] > 0) ? 0.f : -3.0e38f;
#pragma unroll
        for (int lt = 0; lt < 4; lt++)
#pragma unroll
            for (int r = 0; r < 4; r++)
                rmax[lt][r] = fmaxf(rmax[lt][r], acc[lt][jt][r] + addend);
    }

    // reduce across the 16 cols (lanes sharing lane>>4)
#pragma unroll
    for (int m = 1; m < 16; m <<= 1)
#pragma unroll
        for (int lt = 0; lt < 4; lt++)
#pragma unroll
            for (int r = 0; r < 4; r++)
                rmax[lt][r] = fmaxf(rmax[lt][r], __shfl_xor(rmax[lt][r], m));

    __syncthreads();                      // done reading LDS tiles
    float* wred = (float*)qsh;            // alias: 256 floats
    if (lrow == 0) {
#pragma unroll
        for (int lt = 0; lt < 4; lt++)
#pragma unroll
            for (int r = 0; r < 4; r++)
                wred[wc * 128 + wr * 64 + lt * 16 + lk * 4 + r] = rmax[lt][r];
    }
    __syncthreads();
    if (t < 128)
        Mpart[(size_t)(jt16 * 16 + bh) * L_ + l0 + t] =
            fmaxf(wred[t], wred[128 + t]);
}

// ---------------------------------------------------------------------------
// Argmax stage 1 (q reconstructed hi+lo; 16 Mpart slices)
// ---------------------------------------------------------------------------
__global__ __launch_bounds__(256) void argmax1_kernel(
    const f16* __restrict__ qh, const f16* __restrict__ ql,
    const float* __restrict__ kbar_part, const float* __restrict__ Mpart,
    float* __restrict__ bestv, int* __restrict__ besti)
{
    const int bh = blockIdx.x, c = blockIdx.y;
    const int b = bh >> 3, h = bh & 7;
    const int l0 = c * 256;
    const int t = threadIdx.x;

    __shared__ float kb[64];
    if (t < 64) {
        float s = 0.f;
#pragma unroll
        for (int p = 0; p < 8; p++) s += kbar_part[(size_t)(bh * 8 + p) * 64 + t];
        kb[t] = s * (1.0f / (float)S_);
    }
    __syncthreads();

    const int l = l0 + t;
    const f16* qrh = qh + (size_t)(b * L_ + l) * D_ + h * DK;
    const f16* qrl = ql + (size_t)(b * L_ + l) * D_ + h * DK;
    float dot = 0.f;
#pragma unroll
    for (int cc = 0; cc < 8; cc++) {
        const f16x8 hv = *(const f16x8*)&qrh[cc * 8];
        const f16x8 lv = *(const f16x8*)&qrl[cc * 8];
#pragma unroll
        for (int i = 0; i < 8; i++)
            dot += ((float)hv[i] + (float)lv[i]) * kb[cc * 8 + i];
    }
    float mx = Mpart[(size_t)(0 * 16 + bh) * L_ + l];
#pragma unroll
    for (int p = 1; p < MP_SLICES; p++)
        mx = fmaxf(mx, Mpart[(size_t)(p * 16 + bh) * L_ + l]);
    const float val = mx - dot;

    __shared__ float bvs[256];
    __shared__ int bis[256];
    bvs[t] = val; bis[t] = l;
    __syncthreads();
    for (int s = 128; s > 0; s >>= 1) {
        if (t < s) {
            const float ov = bvs[t + s]; const int oi = bis[t + s];
            if (ov > bvs[t] || (ov == bvs[t] && oi < bis[t])) { bvs[t] = ov; bis[t] = oi; }
        }
        __syncthreads();
    }
    if (t == 0) { bestv[bh * 8 + c] = bvs[0]; besti[bh * 8 + c] = bis[0]; }
}

// ---------------------------------------------------------------------------
__global__ void argmax2_kernel(const float* __restrict__ bestv,
                               const int* __restrict__ besti, int* __restrict__ U)
{
    const int t = threadIdx.x;
    if (t < 16) {
        float best = -3.9e38f;
        int bi = 0;
#pragma unroll
        for (int c = 0; c < 8; c++) {
            const float v = bestv[t * 8 + c];
            if (v > best) { best = v; bi = besti[t * 8 + c]; }
        }
        U[t] = bi;
    }
}

// ---------------------------------------------------------------------------
// ctx stage 1 (q,k reconstructed hi+lo; v fp32)
// ---------------------------------------------------------------------------
__global__ __launch_bounds__(256) void ctx_part_kernel(
    const f16* __restrict__ qh, const f16* __restrict__ ql,
    const f16* __restrict__ kh, const f16* __restrict__ kl,
    const float* __restrict__ v, const int* __restrict__ U,
    float* __restrict__ ctx_part, float* __restrict__ cm, float* __restrict__ cs)
{
    const int bh = blockIdx.x, c = blockIdx.y;   // 16 x 16
    const int b = bh >> 3, h = bh & 7;
    const int l0 = c * 128;
    const int t = threadIdx.x;

    __shared__ float qr[64];
    __shared__ float w[128];
    __shared__ float red[128];
    __shared__ float redc[4][64];

    const int u = U[bh];
    if (t < 64)
        qr[t] = (float)qh[(size_t)(b * L_ + u) * D_ + h * DK + t] +
                (float)ql[(size_t)(b * L_ + u) * D_ + h * DK + t];
    __syncthreads();

    {
        const int row = t >> 1, half = t & 1;
        const size_t off = (size_t)(b * L_ + l0 + row) * D_ + h * DK + half * 32;
        const f16* krh = kh + off;
        const f16* krl = kl + off;
        float dot = 0.f;
#pragma unroll
        for (int cc = 0; cc < 4; cc++) {
            const f16x8 hv = *(const f16x8*)&krh[cc * 8];
            const f16x8 lv = *(const f16x8*)&krl[cc * 8];
#pragma unroll
            for (int i = 0; i < 8; i++)
                dot += ((float)hv[i] + (float)lv[i]) * qr[half * 32 + cc * 8 + i];
        }
        dot += __shfl_xor(dot, 1);
        if (half == 0) w[row] = dot * SCALE;
    }
    __syncthreads();

    if (t < 128) red[t] = w[t];
    __syncthreads();
    for (int s = 64; s > 0; s >>= 1) {
        if (t < s) red[t] = fmaxf(red[t], red[t + s]);
        __syncthreads();
    }
    const float m = red[0];
    __syncthreads();

    if (t < 128) { const float e = expf(w[t] - m); w[t] = e; red[t] = e; }
    __syncthreads();
    for (int s = 64; s > 0; s >>= 1) {
        if (t < s) red[t] += red[t + s];
        __syncthreads();
    }
    const float ssum = red[0];

    const int e = t & 63, lg = t >> 6;
    const float* vb = v + (size_t)(b * L_ + l0) * D_ + h * DK + e;
    float cacc = 0.f;
#pragma unroll 4
    for (int l = lg; l < 128; l += 4) cacc += w[l] * vb[(size_t)l * D_];
    redc[lg][e] = cacc;
    __syncthreads();
    if (t < 64)
        ctx_part[(size_t)(bh * 16 + c) * 64 + t] =
            redc[0][t] + redc[1][t] + redc[2][t] + redc[3][t];
    if (t == 0) { cm[bh * 16 + c] = m; cs[bh * 16 + c] = ssum; }
}

// ---------------------------------------------------------------------------
__global__ void ctx_combine_kernel(const float* __restrict__ ctx_part,
                                   const float* __restrict__ cm,
                                   const float* __restrict__ cs,
                                   float* __restrict__ ctx)
{
    const int bh = blockIdx.x;
    const int e = threadIdx.x;   // 64 threads
    float M = -3.9e38f;
#pragma unroll
    for (int c = 0; c < 16; c++) M = fmaxf(M, cm[bh * 16 + c]);
    float denom = 0.f, acc = 0.f;
#pragma unroll
    for (int c = 0; c < 16; c++) {
        const float f = expf(cm[bh * 16 + c] - M);
        denom += f * cs[bh * 16 + c];
        acc   += f * ctx_part[(size_t)(bh * 16 + c) * 64 + e];
    }
    ctx[bh * 64 + e] = acc / denom;
}

// ---------------------------------------------------------------------------
__global__ __launch_bounds__(256) void out_kernel(
    const float* __restrict__ ctx, const float* __restrict__ Wo,
    const float* __restrict__ bo, float* __restrict__ out)
{
    const int b = blockIdx.x;    // 0..1
    const int sl = blockIdx.y;   // 0..63 (32-row slices)
    const int t = threadIdx.x;
    __shared__ float cb[512];
    __shared__ float row[512];

    cb[t] = ctx[b * 512 + t];
    cb[t + 256] = ctx[b * 512 + 256 + t];
    __syncthreads();

#pragma unroll
    for (int r = 0; r < 2; r++) {
        const int e = t + r * 256;
        const float* wr = Wo + (size_t)e * D_;
        float acc = 0.f;
#pragma unroll 8
        for (int c = 0; c < 128; c++) {
            const float4 wv = *(const float4*)(wr + c * 4);
            acc += wv.x * cb[c * 4] + wv.y * cb[c * 4 + 1] +
                   wv.z * cb[c * 4 + 2] + wv.w * cb[c * 4 + 3];
        }
        row[e] = acc + bo[e];
    }
    __syncthreads();

    const float4* r4 = (const float4*)row;
    float4* o4 = (float4*)(out + ((size_t)b * L_ + sl * 32) * D_);
    for (int i = t; i < 32 * 128; i += 256) {
        const int l = i >> 7, c = i & 127;
        o4[l * 128 + c] = r4[c];
    }
}

// ---------------------------------------------------------------------------
extern "C" void kernel_launch(void* const* d_in, const int* in_sizes, int n_in,
                              void* d_out, int out_size, void* d_ws, size_t ws_size,
                              hipStream_t stream)
{
    const float* x   = (const float*)d_in[0];
    const int* samp  = (const int*)d_in[1];
    const float* Wq  = (const float*)d_in[2];
    const float* bq  = (const float*)d_in[3];
    const float* Wk  = (const float*)d_in[4];
    const float* bk  = (const float*)d_in[5];
    const float* Wv  = (const float*)d_in[6];
    const float* bv  = (const float*)d_in[7];
    const float* Wo  = (const float*)d_in[8];
    const float* bo  = (const float*)d_in[9];
    float* out = (float*)d_out;

    f16* qh = (f16*)d_ws;                    // 2M halves each
    f16* ql = qh + QSZ;
    f16* kh = ql + QSZ;
    f16* kl = kh + QSZ;
    float* v         = (float*)(kl + QSZ);    // 2M floats
    float* Mpart     = v + QSZ;               // 16*16*2048 = 524288
    float* kbar_part = Mpart + MP_SLICES * 16 * L_;  // 8192
    float* ctx_part  = kbar_part + 8192;      // 16384
    float* cm        = ctx_part + 16384;      // 256
    float* cs        = cm + 256;              // 256
    float* bestv     = cs + 256;              // 128
    float* ctx       = bestv + 128;           // 1024
    int* counts      = (int*)(ctx + 1024);    // 2048
    int* besti       = counts + 2048;         // 128
    int* U           = besti + 128;           // 16

    hipMemsetAsync(counts, 0, 2048 * sizeof(int), stream);
    proj_kernel<<<dim3(64, 8, 3), 256, 0, stream>>>(x, Wq, bq, Wk, bk, Wv, bv,
                                                    qh, ql, kh, kl, v);
    hist_kernel<<<40, 256, 0, stream>>>(samp, counts);
    kbar_part_kernel<<<dim3(16, 8), 256, 0, stream>>>(kh, kl, counts, kbar_part);
    mstat_kernel<<<dim3(16, 16, 16), 256, 0, stream>>>(qh, ql, kh, kl, counts, Mpart);
    argmax1_kernel<<<dim3(16, 8), 256, 0, stream>>>(qh, ql, kbar_part, Mpart, bestv, besti);
    argmax2_kernel<<<1, 64, 0, stream>>>(bestv, besti, U);
    ctx_part_kernel<<<dim3(16, 16), 256, 0, stream>>>(qh, ql, kh, kl, v, U,
                                                      ctx_part, cm, cs);
    ctx_combine_kernel<<<16, 64, 0, stream>>>(ctx_part, cm, cs, ctx);
    out_kernel<<<dim3(2, 64), 256, 0, stream>>>(ctx, Wo, bo, out);
}

// Round 4
// 164.806 us; speedup vs baseline: 3.2522x; 1.2751x over previous
//
#include <hip/hip_runtime.h>

#define B_ 2
#define L_ 2048
#define D_ 512
#define H_ 8
#define DK 64
#define S_ 10240
#define SCALE 0.125f
#define MP_SLICES 16

#define QSZ (4096 * 512)  // B_*L_*D_ elements

typedef _Float16 f16;
typedef __attribute__((ext_vector_type(8))) _Float16 f16x8;
typedef __attribute__((ext_vector_type(4))) float f32x4;

// ---------------------------------------------------------------------------
// split x (fp32) -> xh + xl (f16 hi/lo)
// ---------------------------------------------------------------------------
__global__ __launch_bounds__(256) void split_x_kernel(
    const float* __restrict__ x, f16* __restrict__ xh, f16* __restrict__ xl)
{
    const size_t i0 = ((size_t)blockIdx.x * 256 + threadIdx.x) * 8;
    const float4 a = *(const float4*)&x[i0];
    const float4 b = *(const float4*)&x[i0 + 4];
    const float vals[8] = {a.x, a.y, a.z, a.w, b.x, b.y, b.z, b.w};
    union { f16 h[8]; uint4 u; } H, Lo;
#pragma unroll
    for (int j = 0; j < 8; j++) {
        const f16 hh = (f16)vals[j];
        H.h[j] = hh;
        Lo.h[j] = (f16)(vals[j] - (float)hh);
    }
    *(uint4*)&xh[i0] = H.u;
    *(uint4*)&xl[i0] = Lo.u;
}

// ---------------------------------------------------------------------------
// split Wq,Wk -> concat wh/wl [1024][512] f16 hi/lo; biascat[1024] = bq|bk
// ---------------------------------------------------------------------------
__global__ __launch_bounds__(256) void split_w_kernel(
    const float* __restrict__ Wq, const float* __restrict__ Wk,
    const float* __restrict__ bq, const float* __restrict__ bk,
    f16* __restrict__ wh, f16* __restrict__ wl, float* __restrict__ biascat)
{
    const size_t i0 = ((size_t)blockIdx.x * 256 + threadIdx.x) * 8;
    const float* src = (i0 < (size_t)512 * 512) ? Wq + i0 : Wk + (i0 - (size_t)512 * 512);
    const float4 a = *(const float4*)&src[0];
    const float4 b = *(const float4*)&src[4];
    const float vals[8] = {a.x, a.y, a.z, a.w, b.x, b.y, b.z, b.w};
    union { f16 h[8]; uint4 u; } H, Lo;
#pragma unroll
    for (int j = 0; j < 8; j++) {
        const f16 hh = (f16)vals[j];
        H.h[j] = hh;
        Lo.h[j] = (f16)(vals[j] - (float)hh);
    }
    *(uint4*)&wh[i0] = H.u;
    *(uint4*)&wl[i0] = Lo.u;
    if (blockIdx.x == 0)
        for (int e = threadIdx.x; e < 1024; e += 256)
            biascat[e] = (e < 512) ? bq[e] : bk[e - 512];
}

// ---------------------------------------------------------------------------
// q,k projections via split-f16 MFMA GEMM: [4096 x 512] . [512 x 1024]^T
// (B rows = Wq|Wk rows).  Outputs f16 hi/lo splits directly.
// ---------------------------------------------------------------------------
__global__ __launch_bounds__(256) void projqk_kernel(
    const f16* __restrict__ xh, const f16* __restrict__ xl,
    const f16* __restrict__ wh, const f16* __restrict__ wl,
    const float* __restrict__ biascat,
    f16* __restrict__ qh, f16* __restrict__ ql,
    f16* __restrict__ kh, f16* __restrict__ kl)
{
    const int n0 = blockIdx.x * 128;   // rows (tokens)
    const int e0 = blockIdx.y * 128;   // cols (proj dims, 0..1023)
    const int t = threadIdx.x;

    __shared__ __align__(16) f16 lds[4 * 128 * 64];   // 64 KB
    f16* ash = lds;
    f16* asl = lds + 8192;
    f16* bsh = lds + 16384;
    f16* bsl = lds + 24576;

    const int lane = t & 63, wid = t >> 6;
    const int wr = wid >> 1, wc = wid & 1;
    const int lrow = lane & 15, lk = lane >> 4;

    f32x4 acc[4][4];
#pragma unroll
    for (int i = 0; i < 4; i++)
#pragma unroll
        for (int j = 0; j < 4; j++)
#pragma unroll
            for (int r = 0; r < 4; r++) acc[i][j][r] = 0.f;

    for (int kt = 0; kt < 8; kt++) {
        __syncthreads();
#pragma unroll
        for (int i = 0; i < 4; i++) {
            const int g = i * 256 + t;
            const int row = g >> 3, c = g & 7;
            const int cs = c ^ (row & 7);
            const int lo = row * 64 + cs * 8;
            const size_t ga = (size_t)(n0 + row) * 512 + kt * 64 + c * 8;
            const size_t gb = (size_t)(e0 + row) * 512 + kt * 64 + c * 8;
            *(uint4*)&ash[lo] = *(const uint4*)&xh[ga];
            *(uint4*)&asl[lo] = *(const uint4*)&xl[ga];
            *(uint4*)&bsh[lo] = *(const uint4*)&wh[gb];
            *(uint4*)&bsl[lo] = *(const uint4*)&wl[gb];
        }
        __syncthreads();

#pragma unroll
        for (int kk = 0; kk < 2; kk++) {
            f16x8 ah[4], al[4], bh_[4], bl_[4];
#pragma unroll
            for (int lt = 0; lt < 4; lt++) {
                const int row = wr * 64 + lt * 16 + lrow;
                const int cs = (kk * 4 + lk) ^ (row & 7);
                const int o = row * 64 + cs * 8;
                ah[lt] = *(const f16x8*)&ash[o];
                al[lt] = *(const f16x8*)&asl[o];
            }
#pragma unroll
            for (int jt = 0; jt < 4; jt++) {
                const int row = wc * 64 + jt * 16 + lrow;
                const int cs = (kk * 4 + lk) ^ (row & 7);
                const int o = row * 64 + cs * 8;
                bh_[jt] = *(const f16x8*)&bsh[o];
                bl_[jt] = *(const f16x8*)&bsl[o];
            }
#pragma unroll
            for (int lt = 0; lt < 4; lt++)
#pragma unroll
                for (int jt = 0; jt < 4; jt++) {
                    acc[lt][jt] = __builtin_amdgcn_mfma_f32_16x16x32_f16(
                        ah[lt], bh_[jt], acc[lt][jt], 0, 0, 0);
                    acc[lt][jt] = __builtin_amdgcn_mfma_f32_16x16x32_f16(
                        ah[lt], bl_[jt], acc[lt][jt], 0, 0, 0);
                    acc[lt][jt] = __builtin_amdgcn_mfma_f32_16x16x32_f16(
                        al[lt], bh_[jt], acc[lt][jt], 0, 0, 0);
                }
        }
    }

    // Epilogue: bias add, split to hi/lo, LDS transpose for coalesced stores.
    const int PSTR = 72;   // f16 row stride (16B-aligned rows)
    f16* tile = lds + wid * 64 * PSTR;
    const int ebase = e0 + wc * 64;
    const bool isQ = (blockIdx.y < 4);
    const int colbase = (blockIdx.y & 3) * 128;

#pragma unroll
    for (int round = 0; round < 2; round++) {
        __syncthreads();
#pragma unroll
        for (int jt = 0; jt < 4; jt++) {
            const float bval = biascat[ebase + jt * 16 + lrow];
#pragma unroll
            for (int lt = 0; lt < 4; lt++)
#pragma unroll
                for (int r = 0; r < 4; r++) {
                    const float y = acc[lt][jt][r] + bval;
                    const f16 hi = (f16)y;
                    const f16 val = (round == 0) ? hi : (f16)(y - (float)hi);
                    tile[(lt * 16 + lk * 4 + r) * PSTR + jt * 16 + lrow] = val;
                }
        }
        __syncthreads();
        f16* dst = isQ ? ((round == 0) ? qh : ql) : ((round == 0) ? kh : kl);
        for (int i = t; i < 2048; i += 256) {
            const int w = i >> 9, rem = i & 511, row = rem >> 3, c = rem & 7;
            const int n = n0 + (w >> 1) * 64 + row;
            const int col = colbase + (w & 1) * 64 + c * 8;
            *(uint4*)&dst[(size_t)n * 512 + col] =
                *(const uint4*)&lds[w * 64 * PSTR + row * PSTR + c * 8];
        }
    }
}

// ---------------------------------------------------------------------------
__global__ void hist_kernel(const int* __restrict__ samp, int* __restrict__ counts)
{
    const int i = blockIdx.x * 256 + threadIdx.x;
    if (i < S_) atomicAdd(&counts[samp[i]], 1);
}

// ---------------------------------------------------------------------------
__global__ __launch_bounds__(256) void kbar_part_kernel(
    const f16* __restrict__ kh, const f16* __restrict__ kl,
    const int* __restrict__ counts, float* __restrict__ kbar_part)
{
    const int bh = blockIdx.x, c = blockIdx.y;
    const int b = bh >> 3, h = bh & 7;
    const int j0 = c * 256;
    const int t = threadIdx.x;
    const int e = t & 63, jg = t >> 6;
    const f16* kbh = kh + (size_t)b * L_ * D_ + h * DK + e;
    const f16* kbl = kl + (size_t)b * L_ * D_ + h * DK + e;
    float s = 0.f;
    for (int j = j0 + jg; j < j0 + 256; j += 4) {
        const float kv = (float)kbh[(size_t)j * D_] + (float)kbl[(size_t)j * D_];
        s += (float)counts[j] * kv;
    }
    __shared__ float red[4][64];
    red[jg][e] = s;
    __syncthreads();
    if (t < 64)
        kbar_part[(size_t)(bh * 8 + c) * 64 + t] =
            red[0][t] + red[1][t] + red[2][t] + red[3][t];
}

// ---------------------------------------------------------------------------
// mstat via split-f16 MFMA: masked row-max of Q.K^T (unscaled)
// ---------------------------------------------------------------------------
__global__ __launch_bounds__(256) void mstat_kernel(
    const f16* __restrict__ qh, const f16* __restrict__ ql,
    const f16* __restrict__ kh, const f16* __restrict__ kl,
    const int* __restrict__ counts, float* __restrict__ Mpart)
{
    const int lt16 = blockIdx.x;
    const int bh   = blockIdx.y;
    const int jt16 = blockIdx.z;
    const int b = bh >> 3, h = bh & 7;
    const int l0 = lt16 * 128, j0 = jt16 * 128;
    const int t = threadIdx.x;

    __shared__ __align__(16) f16 qsh[128 * 64];
    __shared__ __align__(16) f16 qsl[128 * 64];
    __shared__ __align__(16) f16 ksh[128 * 64];
    __shared__ __align__(16) f16 ksl[128 * 64];

    {
        const size_t qbase = (size_t)(b * L_ + l0) * D_ + h * DK;
        const size_t kbase = (size_t)(b * L_ + j0) * D_ + h * DK;
#pragma unroll
        for (int i = 0; i < 4; i++) {
            const int g = i * 256 + t;
            const int row = g >> 3, c = g & 7;
            const int cs = c ^ (row & 7);
            const size_t go = (size_t)row * D_ + c * 8;
            const int lo = row * 64 + cs * 8;
            *(uint4*)&qsh[lo] = *(const uint4*)&qh[qbase + go];
            *(uint4*)&qsl[lo] = *(const uint4*)&ql[qbase + go];
            *(uint4*)&ksh[lo] = *(const uint4*)&kh[kbase + go];
            *(uint4*)&ksl[lo] = *(const uint4*)&kl[kbase + go];
        }
    }
    __syncthreads();

    const int lane = t & 63, wid = t >> 6;
    const int wr = wid >> 1, wc = wid & 1;
    const int lrow = lane & 15, lk = lane >> 4;

    f32x4 acc[4][4];
#pragma unroll
    for (int i = 0; i < 4; i++)
#pragma unroll
        for (int j = 0; j < 4; j++)
#pragma unroll
            for (int r = 0; r < 4; r++) acc[i][j][r] = 0.f;

#pragma unroll
    for (int kk = 0; kk < 2; kk++) {
        f16x8 ah[4], al[4], bh_[4], bl_[4];
#pragma unroll
        for (int lt = 0; lt < 4; lt++) {
            const int row = wr * 64 + lt * 16 + lrow;
            const int cs = (kk * 4 + lk) ^ (row & 7);
            const int o = row * 64 + cs * 8;
            ah[lt] = *(const f16x8*)&qsh[o];
            al[lt] = *(const f16x8*)&qsl[o];
        }
#pragma unroll
        for (int jt = 0; jt < 4; jt++) {
            const int row = wc * 64 + jt * 16 + lrow;
            const int cs = (kk * 4 + lk) ^ (row & 7);
            const int o = row * 64 + cs * 8;
            bh_[jt] = *(const f16x8*)&ksh[o];
            bl_[jt] = *(const f16x8*)&ksl[o];
        }
#pragma unroll
        for (int lt = 0; lt < 4; lt++)
#pragma unroll
            for (int jt = 0; jt < 4; jt++) {
                acc[lt][jt] = __builtin_amdgcn_mfma_f32_16x16x32_f16(
                    ah[lt], bh_[jt], acc[lt][jt], 0, 0, 0);
                acc[lt][jt] = __builtin_amdgcn_mfma_f32_16x16x32_f16(
                    ah[lt], bl_[jt], acc[lt][jt], 0, 0, 0);
                acc[lt][jt] = __builtin_amdgcn_mfma_f32_16x16x32_f16(
                    al[lt], bh_[jt], acc[lt][jt], 0, 0, 0);
            }
    }

    float rmax[4][4];
#pragma unroll
    for (int lt = 0; lt < 4; lt++)
#pragma unroll
        for (int r = 0; r < 4; r++) rmax[lt][r] = -3.9e38f;

#pragma unroll
    for (int jt = 0; jt < 4; jt++) {
        const int cj = j0 + wc * 64 + jt * 16 + lrow;
        const float addend = (counts[cj] > 0) ? 0.f : -3.0e38f;
#pragma unroll
        for (int lt = 0; lt < 4; lt++)
#pragma unroll
            for (int r = 0; r < 4; r++)
                rmax[lt][r] = fmaxf(rmax[lt][r], acc[lt][jt][r] + addend);
    }

#pragma unroll
    for (int m = 1; m < 16; m <<= 1)
#pragma unroll
        for (int lt = 0; lt < 4; lt++)
#pragma unroll
            for (int r = 0; r < 4; r++)
                rmax[lt][r] = fmaxf(rmax[lt][r], __shfl_xor(rmax[lt][r], m));

    __syncthreads();
    float* wred = (float*)qsh;
    if (lrow == 0) {
#pragma unroll
        for (int lt = 0; lt < 4; lt++)
#pragma unroll
            for (int r = 0; r < 4; r++)
                wred[wc * 128 + wr * 64 + lt * 16 + lk * 4 + r] = rmax[lt][r];
    }
    __syncthreads();
    if (t < 128)
        Mpart[(size_t)(jt16 * 16 + bh) * L_ + l0 + t] =
            fmaxf(wred[t], wred[128 + t]);
}

// ---------------------------------------------------------------------------
__global__ __launch_bounds__(256) void argmax1_kernel(
    const f16* __restrict__ qh, const f16* __restrict__ ql,
    const float* __restrict__ kbar_part, const float* __restrict__ Mpart,
    float* __restrict__ bestv, int* __restrict__ besti)
{
    const int bh = blockIdx.x, c = blockIdx.y;
    const int b = bh >> 3, h = bh & 7;
    const int l0 = c * 256;
    const int t = threadIdx.x;

    __shared__ float kb[64];
    if (t < 64) {
        float s = 0.f;
#pragma unroll
        for (int p = 0; p < 8; p++) s += kbar_part[(size_t)(bh * 8 + p) * 64 + t];
        kb[t] = s * (1.0f / (float)S_);
    }
    __syncthreads();

    const int l = l0 + t;
    const f16* qrh = qh + (size_t)(b * L_ + l) * D_ + h * DK;
    const f16* qrl = ql + (size_t)(b * L_ + l) * D_ + h * DK;
    float dot = 0.f;
#pragma unroll
    for (int cc = 0; cc < 8; cc++) {
        const f16x8 hv = *(const f16x8*)&qrh[cc * 8];
        const f16x8 lv = *(const f16x8*)&qrl[cc * 8];
#pragma unroll
        for (int i = 0; i < 8; i++)
            dot += ((float)hv[i] + (float)lv[i]) * kb[cc * 8 + i];
    }
    float mx = Mpart[(size_t)(0 * 16 + bh) * L_ + l];
#pragma unroll
    for (int p = 1; p < MP_SLICES; p++)
        mx = fmaxf(mx, Mpart[(size_t)(p * 16 + bh) * L_ + l]);
    const float val = mx - dot;

    __shared__ float bvs[256];
    __shared__ int bis[256];
    bvs[t] = val; bis[t] = l;
    __syncthreads();
    for (int s = 128; s > 0; s >>= 1) {
        if (t < s) {
            const float ov = bvs[t + s]; const int oi = bis[t + s];
            if (ov > bvs[t] || (ov == bvs[t] && oi < bis[t])) { bvs[t] = ov; bis[t] = oi; }
        }
        __syncthreads();
    }
    if (t == 0) { bestv[bh * 8 + c] = bvs[0]; besti[bh * 8 + c] = bis[0]; }
}

// ---------------------------------------------------------------------------
__global__ void argmax2_kernel(const float* __restrict__ bestv,
                               const int* __restrict__ besti, int* __restrict__ U)
{
    const int t = threadIdx.x;
    if (t < 16) {
        float best = -3.9e38f;
        int bi = 0;
#pragma unroll
        for (int c = 0; c < 8; c++) {
            const float v = bestv[t * 8 + c];
            if (v > best) { best = v; bi = besti[t * 8 + c]; }
        }
        U[t] = bi;
    }
}

// ---------------------------------------------------------------------------
// ctx stage 1: scores from kh/kl . q_u, softmax partials, x-weighted partial
// (context = (sum_l attn_l x_l) . Wv + bv  since sum attn = 1)
// ---------------------------------------------------------------------------
__global__ __launch_bounds__(256) void ctx_part_kernel(
    const f16* __restrict__ qh, const f16* __restrict__ ql,
    const f16* __restrict__ kh, const f16* __restrict__ kl,
    const float* __restrict__ x, const int* __restrict__ U,
    float* __restrict__ xbar_part, float* __restrict__ cm, float* __restrict__ cs)
{
    const int bh = blockIdx.x, c = blockIdx.y;   // 16 x 16
    const int b = bh >> 3, h = bh & 7;
    const int l0 = c * 128;
    const int t = threadIdx.x;

    __shared__ float qr[64];
    __shared__ float w[128];
    __shared__ float red[128];

    const int u = U[bh];
    if (t < 64)
        qr[t] = (float)qh[(size_t)(b * L_ + u) * D_ + h * DK + t] +
                (float)ql[(size_t)(b * L_ + u) * D_ + h * DK + t];
    __syncthreads();

    {
        const int row = t >> 1, half = t & 1;
        const size_t off = (size_t)(b * L_ + l0 + row) * D_ + h * DK + half * 32;
        const f16* krh = kh + off;
        const f16* krl = kl + off;
        float dot = 0.f;
#pragma unroll
        for (int cc = 0; cc < 4; cc++) {
            const f16x8 hv = *(const f16x8*)&krh[cc * 8];
            const f16x8 lv = *(const f16x8*)&krl[cc * 8];
#pragma unroll
            for (int i = 0; i < 8; i++)
                dot += ((float)hv[i] + (float)lv[i]) * qr[half * 32 + cc * 8 + i];
        }
        dot += __shfl_xor(dot, 1);
        if (half == 0) w[row] = dot * SCALE;
    }
    __syncthreads();

    if (t < 128) red[t] = w[t];
    __syncthreads();
    for (int s = 64; s > 0; s >>= 1) {
        if (t < s) red[t] = fmaxf(red[t], red[t + s]);
        __syncthreads();
    }
    const float m = red[0];
    __syncthreads();

    if (t < 128) { const float e = expf(w[t] - m); w[t] = e; red[t] = e; }
    __syncthreads();
    for (int s = 64; s > 0; s >>= 1) {
        if (t < s) red[t] += red[t + s];
        __syncthreads();
    }
    const float ssum = red[0];

    // x-weighted partial: thread owns cols 2t, 2t+1
    float ax = 0.f, ay = 0.f;
    const float* xb = x + (size_t)(b * L_ + l0) * D_ + t * 2;
#pragma unroll 4
    for (int l = 0; l < 128; l++) {
        const float wl = w[l];
        const float2 xv = *(const float2*)(xb + (size_t)l * D_);
        ax = fmaf(wl, xv.x, ax);
        ay = fmaf(wl, xv.y, ay);
    }
    float2 st; st.x = ax; st.y = ay;
    *(float2*)&xbar_part[(size_t)(bh * 16 + c) * 512 + t * 2] = st;
    if (t == 0) { cm[bh * 16 + c] = m; cs[bh * 16 + c] = ssum; }
}

// ---------------------------------------------------------------------------
// combine partials -> xbar, then ctx[bh] slice = xbar . Wv(h rows) + bv
// ---------------------------------------------------------------------------
__global__ __launch_bounds__(256) void ctx_combine_kernel(
    const float* __restrict__ xbar_part, const float* __restrict__ cm,
    const float* __restrict__ cs, const float* __restrict__ Wv,
    const float* __restrict__ bv, float* __restrict__ ctx)
{
    const int bh = blockIdx.x;
    const int h = bh & 7;
    const int t = threadIdx.x;
    __shared__ float xbar[512];

    float M = -3.9e38f;
#pragma unroll
    for (int c = 0; c < 16; c++) M = fmaxf(M, cm[bh * 16 + c]);
    float denom = 0.f;
    float ax = 0.f, ay = 0.f;
#pragma unroll
    for (int c = 0; c < 16; c++) {
        const float f = expf(cm[bh * 16 + c] - M);
        denom += f * cs[bh * 16 + c];
        const float2 p = *(const float2*)&xbar_part[(size_t)(bh * 16 + c) * 512 + t * 2];
        ax = fmaf(f, p.x, ax);
        ay = fmaf(f, p.y, ay);
    }
    xbar[t * 2] = ax; xbar[t * 2 + 1] = ay;
    __syncthreads();

    if (t < 64) {
        const float* wr = Wv + (size_t)(h * 64 + t) * D_;
        float acc = 0.f;
#pragma unroll 8
        for (int d = 0; d < 128; d++) {
            const float4 wv4 = *(const float4*)&wr[d * 4];
            acc += wv4.x * xbar[d * 4] + wv4.y * xbar[d * 4 + 1] +
                   wv4.z * xbar[d * 4 + 2] + wv4.w * xbar[d * 4 + 3];
        }
        ctx[bh * 64 + t] = acc / denom + bv[h * 64 + t];
    }
}

// ---------------------------------------------------------------------------
__global__ __launch_bounds__(256) void out_kernel(
    const float* __restrict__ ctx, const float* __restrict__ Wo,
    const float* __restrict__ bo, float* __restrict__ out)
{
    const int b = blockIdx.x;    // 0..1
    const int sl = blockIdx.y;   // 0..63 (32-row slices)
    const int t = threadIdx.x;
    __shared__ float cb[512];
    __shared__ float row[512];

    cb[t] = ctx[b * 512 + t];
    cb[t + 256] = ctx[b * 512 + 256 + t];
    __syncthreads();

#pragma unroll
    for (int r = 0; r < 2; r++) {
        const int e = t + r * 256;
        const float* wr = Wo + (size_t)e * D_;
        float acc = 0.f;
#pragma unroll 8
        for (int c = 0; c < 128; c++) {
            const float4 wv = *(const float4*)(wr + c * 4);
            acc += wv.x * cb[c * 4] + wv.y * cb[c * 4 + 1] +
                   wv.z * cb[c * 4 + 2] + wv.w * cb[c * 4 + 3];
        }
        row[e] = acc + bo[e];
    }
    __syncthreads();

    const float4* r4 = (const float4*)row;
    float4* o4 = (float4*)(out + ((size_t)b * L_ + sl * 32) * D_);
    for (int i = t; i < 32 * 128; i += 256) {
        const int l = i >> 7, c = i & 127;
        o4[l * 128 + c] = r4[c];
    }
}

// ---------------------------------------------------------------------------
extern "C" void kernel_launch(void* const* d_in, const int* in_sizes, int n_in,
                              void* d_out, int out_size, void* d_ws, size_t ws_size,
                              hipStream_t stream)
{
    const float* x   = (const float*)d_in[0];
    const int* samp  = (const int*)d_in[1];
    const float* Wq  = (const float*)d_in[2];
    const float* bq  = (const float*)d_in[3];
    const float* Wk  = (const float*)d_in[4];
    const float* bk  = (const float*)d_in[5];
    const float* Wv  = (const float*)d_in[6];
    const float* bv  = (const float*)d_in[7];
    const float* Wo  = (const float*)d_in[8];
    const float* bo  = (const float*)d_in[9];
    float* out = (float*)d_out;

    f16* qh = (f16*)d_ws;
    f16* ql = qh + QSZ;
    f16* kh = ql + QSZ;
    f16* kl = kh + QSZ;
    f16* xh = kl + QSZ;
    f16* xl = xh + QSZ;
    f16* wh = xl + QSZ;                       // 1024*512
    f16* wl = wh + 1024 * 512;
    float* fbase     = (float*)(wl + 1024 * 512);
    float* biascat   = fbase;                 // 1024
    float* Mpart     = biascat + 1024;        // 16*16*2048 = 524288
    float* kbar_part = Mpart + MP_SLICES * 16 * L_;  // 8192
    float* xbar_part = kbar_part + 8192;      // 16*16*512 = 131072
    float* cm        = xbar_part + 131072;    // 256
    float* cs        = cm + 256;              // 256
    float* bestv     = cs + 256;              // 128
    float* ctx       = bestv + 128;           // 1024
    int* counts      = (int*)(ctx + 1024);    // 2048
    int* besti       = counts + 2048;         // 128
    int* U           = besti + 128;           // 16

    hipMemsetAsync(counts, 0, 2048 * sizeof(int), stream);
    split_x_kernel<<<1024, 256, 0, stream>>>(x, xh, xl);
    split_w_kernel<<<256, 256, 0, stream>>>(Wq, Wk, bq, bk, wh, wl, biascat);
    projqk_kernel<<<dim3(32, 8), 256, 0, stream>>>(xh, xl, wh, wl, biascat,
                                                   qh, ql, kh, kl);
    hist_kernel<<<40, 256, 0, stream>>>(samp, counts);
    kbar_part_kernel<<<dim3(16, 8), 256, 0, stream>>>(kh, kl, counts, kbar_part);
    mstat_kernel<<<dim3(16, 16, 16), 256, 0, stream>>>(qh, ql, kh, kl, counts, Mpart);
    argmax1_kernel<<<dim3(16, 8), 256, 0, stream>>>(qh, ql, kbar_part, Mpart, bestv, besti);
    argmax2_kernel<<<1, 64, 0, stream>>>(bestv, besti, U);
    ctx_part_kernel<<<dim3(16, 16), 256, 0, stream>>>(qh, ql, kh, kl, x, U,
                                                      xbar_part, cm, cs);
    ctx_combine_kernel<<<16, 256, 0, stream>>>(xbar_part, cm, cs, Wv, bv, ctx);
    out_kernel<<<dim3(2, 64), 256, 0, stream>>>(ctx, Wo, bo, out);
}